// Round 8
// baseline (324.683 us; speedup 1.0000x reference)
//
#include <hip/hip_runtime.h>

#define SUPPORT 512
#define TARGET  65024
#define NCLS    64
#define NQUAD   (TARGET / 4)       // 16256 row-quads for direct part
#define GS_ROWS 64
#define GS_BLK  (TARGET / GS_ROWS) // 1016 stream blocks
#define PH_BLK  2032               // pos_hist blocks (8 threads/row)
#define DR_BLK  1024               // direct blocks

struct Accum {
    // ---- zeroed by prep ----
    float hist_pos_sp[8][80];
    float sum_all[8];
    float sum_pos[8];
    float nll_sum[8];
    int   tgt_cnt[NCLS];
    // ---- fully overwritten, no zeroing needed ----
    float A[80];                // C[idx+1]
    float B[80];                // Hpos[idx+1]
    int   sup_cnt[NCLS];
    int   cls_off[NCLS + 1];
    int   cls_col[SUPPORT];
};
#define ZERO_WORDS ((8 * 80 * 4 + 3 * 8 * 4 + NCLS * 4) / 4)   // 728 words

__device__ __forceinline__ void lds_fadd(float* p, float v) {
    __hip_atomic_fetch_add(p, v, __ATOMIC_RELAXED, __HIP_MEMORY_SCOPE_WORKGROUP);
}

// ---------------------------------------------------------------- prep (zeroes ws too)
__global__ void prep_kernel(const int* __restrict__ labels, Accum* ws) {
    __shared__ int sh_cnt[NCLS], sh_off[NCLS], cur[NCLS];
    const int t = threadIdx.x;                 // 512 threads
    int* wsi = (int*)ws;
    for (int i = t; i < ZERO_WORDS; i += 512) wsi[i] = 0;
    if (t < NCLS) { sh_cnt[t] = 0; cur[t] = 0; }
    __syncthreads();
    const int c = labels[t];
    atomicAdd(&sh_cnt[c], 1);
    __syncthreads();
    if (t == 0) {
        int o = 0;
        for (int i = 0; i < NCLS; ++i) { sh_off[i] = o; ws->cls_off[i] = o; o += sh_cnt[i]; }
        ws->cls_off[NCLS] = o;
    }
    __syncthreads();
    if (t < NCLS) ws->sup_cnt[t] = sh_cnt[t];
    const int slot = atomicAdd(&cur[c], 1);
    ws->cls_col[sh_off[c] + slot] = t;
}

// ---------------------------------------------------------------- pos_hist + direct (fused dispatch)
__global__ __launch_bounds__(256) void phdir_kernel(const float* __restrict__ ip,
                                                    const float* __restrict__ logits,
                                                    const int* __restrict__ labels,
                                                    Accum* __restrict__ ws) {
    const int tid = threadIdx.x;
    if (blockIdx.x < PH_BLK) {
        // ---- pos histogram: 8 threads per target row gather positive columns
        __shared__ float hp[77][8];
        __shared__ int   colL[SUPPORT];
        __shared__ int   offL[NCLS + 1];
        for (int i = tid; i < 77 * 8; i += 256) (&hp[0][0])[i] = 0.0f;
        for (int i = tid; i < SUPPORT; i += 256) colL[i] = ws->cls_col[i];
        if (tid <= NCLS) offL[tid] = ws->cls_off[tid];
        __syncthreads();

        const int row = (blockIdx.x * 256 + tid) >> 3;
        const int sl  = tid & 7;
        {
            const int c    = labels[SUPPORT + row];
            const int base = offL[c];
            const int cnt  = offL[c + 1] - base;
            const float* rptr = ip + (size_t)row * SUPPORT;
            for (int j = sl; j < cnt; j += 8) {
                const float s  = rptr[colL[base + j]];
                const float u  = s * 75.0f;
                const float fl = floorf(u);
                const float fr = u - fl;
                const int idx  = (int)fl;
                lds_fadd(&hp[idx][sl],     fr);
                lds_fadd(&hp[idx + 1][sl], 1.0f - fr);
            }
        }
        __syncthreads();
        if (tid < 76) {
            float s = 0.0f;
            #pragma unroll
            for (int r = 0; r < 8; ++r) s += hp[tid][r];
            if (s != 0.0f) unsafeAtomicAdd(&ws->hist_pos_sp[blockIdx.x & 7][tid], s);
        }
    } else {
        // ---- direct loss: 4 rows per wave, 16-lane group per row
        __shared__ int   ltc[NCLS];
        __shared__ float wsum[4];
        if (tid < NCLS) ltc[tid] = 0;
        __syncthreads();

        const int bid  = blockIdx.x - PH_BLK;
        const int wid  = tid >> 6;
        const int lane = tid & 63;
        const int sub  = lane >> 4;
        const int grpb = lane & ~15;

        float lsum = 0.0f;
        for (int q = bid * 4 + wid; q < NQUAD; q += DR_BLK * 4) {
            const float4 x = reinterpret_cast<const float4*>(logits)[q * 64 + lane];
            const int lab  = labels[SUPPORT + q * 4 + sub];
            float m = fmaxf(fmaxf(x.x, x.y), fmaxf(x.z, x.w));
            #pragma unroll
            for (int off = 1; off < 16; off <<= 1) m = fmaxf(m, __shfl_xor(m, off));
            float e = __expf(x.x - m) + __expf(x.y - m) + __expf(x.z - m) + __expf(x.w - m);
            #pragma unroll
            for (int off = 1; off < 16; off <<= 1) e += __shfl_xor(e, off);
            const int l3 = lab & 3;
            const float sel = l3 == 0 ? x.x : l3 == 1 ? x.y : l3 == 2 ? x.z : x.w;
            const float xl = __shfl(sel, grpb + (lab >> 2));
            if ((lane & 15) == 0) {
                lsum += m + __logf(e) - xl;
                atomicAdd(&ltc[lab], 1);
            }
        }
        #pragma unroll
        for (int off = 1; off < 64; off <<= 1) lsum += __shfl_xor(lsum, off);
        if (lane == 0) wsum[wid] = lsum;
        __syncthreads();
        if (tid == 0)
            unsafeAtomicAdd(&ws->nll_sum[bid & 7], wsum[0] + wsum[1] + wsum[2] + wsum[3]);
        if (tid < NCLS) {
            int v = ltc[tid];
            if (v) atomicAdd(&ws->tgt_cnt[tid], v);
        }
    }
}

// ---------------------------------------------------------------- cdf build
__global__ void cdf_kernel(Accum* ws) {
    __shared__ float H[80];
    const int t = threadIdx.x;
    if (t < 76) {
        float s = 0.0f;
        #pragma unroll
        for (int r = 0; r < 8; ++r) s += ws->hist_pos_sp[r][t];
        H[t] = s;
    }
    if (t >= 76 && t < 80) H[t] = 0.0f;
    __syncthreads();
    if (t == 0) {
        float C[77];
        float cacc = 0.0f;
        for (int i = 0; i < 76; ++i) { cacc += H[i]; C[i] = cacc; }
        for (int idx = 0; idx < 75; ++idx) { ws->A[idx] = C[idx + 1]; ws->B[idx] = H[idx + 1]; }
        ws->A[75] = C[75]; ws->B[75] = 0.0f;
        for (int i = 76; i < 80; ++i) { ws->A[i] = 0.0f; ws->B[i] = 0.0f; }
    }
}

// ---------------------------------------------------------------- main pass
// Block owns 64 contiguous rows (32 steps x 256 float4). Named-register 8-deep
// load pipeline, mask-free, clamp-free inner loop: ~9 VALU + 1 ds_read_b64 per
// element. Epilogue: block re-reads its OWN rows' positive columns (L2-hot)
// via CSR to accumulate sum_pos.
__global__ __launch_bounds__(256, 3) void gather_kernel(const float* __restrict__ ip,
                                                        const int* __restrict__ labels,
                                                        const int* __restrict__ cls_off,
                                                        const int* __restrict__ cls_col,
                                                        Accum* __restrict__ ws) {
    __shared__ float2 tab[76 * 16];   // 16-way replicated, idx-staggered
    __shared__ float red[8];
    const int tid = threadIdx.x;
    const int c16 = tid & 15;

    for (int i = tid; i < 76 * 16; i += 256) {
        const int idx = i >> 4, cc = i & 15;
        tab[(idx << 4) + ((cc + idx) & 15)] = make_float2(ws->A[idx], ws->B[idx]);
    }
    __syncthreads();

    const int row0 = blockIdx.x * GS_ROWS;
    const float4* base = reinterpret_cast<const float4*>(ip)
                       + (size_t)row0 * 128 + tid;

    float s0 = 0.0f, s1 = 0.0f;
    float4 qa0, qa1, qa2, qa3, qa4, qa5, qa6, qa7;
    float4 qb0, qb1, qb2, qb3, qb4, qb5, qb6, qb7;

#define LDA(T) { qa0 = base[((T)+0)*256]; qa1 = base[((T)+1)*256]; \
                 qa2 = base[((T)+2)*256]; qa3 = base[((T)+3)*256]; \
                 qa4 = base[((T)+4)*256]; qa5 = base[((T)+5)*256]; \
                 qa6 = base[((T)+6)*256]; qa7 = base[((T)+7)*256]; }
#define LDB(T) { qb0 = base[((T)+0)*256]; qb1 = base[((T)+1)*256]; \
                 qb2 = base[((T)+2)*256]; qb3 = base[((T)+3)*256]; \
                 qb4 = base[((T)+4)*256]; qb5 = base[((T)+5)*256]; \
                 qb6 = base[((T)+6)*256]; qb7 = base[((T)+7)*256]; }
#define PE(S, ACC) { const float u = (S) * 75.0f; const float fl = floorf(u);     \
                     const float fr = u - fl; const int idx = (int)fl;            \
                     const float2 ab = tab[(idx << 4) + ((c16 + idx) & 15)];      \
                     ACC += fmaf(-fr, ab.y, ab.x); }
#define P1(Q) { PE(Q.x, s0) PE(Q.y, s1) PE(Q.z, s0) PE(Q.w, s1) }
#define PA()  { P1(qa0) P1(qa1) P1(qa2) P1(qa3) P1(qa4) P1(qa5) P1(qa6) P1(qa7) }
#define PB()  { P1(qb0) P1(qb1) P1(qb2) P1(qb3) P1(qb4) P1(qb5) P1(qb6) P1(qb7) }

    LDA(0);
    LDB(8);
    PA();  LDA(16);
    PB();  LDB(24);
    PA();
    PB();

#undef LDA
#undef LDB
#undef PE
#undef P1
#undef PA
#undef PB

    // ---- epilogue: positive columns of this block's own rows (L2-hot)
    float s_pos = 0.0f;
    {
        const int r   = row0 + (tid >> 2);     // 4 threads per row
        const int sub = tid & 3;
        const int c   = labels[SUPPORT + r];
        const int b0  = cls_off[c];
        const int end = cls_off[c + 1];
        const float* rp = ip + (size_t)r * SUPPORT;
        for (int j = b0 + sub; j < end; j += 4) {
            const float s  = rp[cls_col[j]];
            const float u  = s * 75.0f;
            const float fl = floorf(u);
            const float fr = u - fl;
            const int idx  = (int)fl;
            const float2 ab = tab[(idx << 4) + ((c16 + idx) & 15)];
            s_pos += fmaf(-fr, ab.y, ab.x);
        }
    }

    float s_all = s0 + s1;
    #pragma unroll
    for (int off = 1; off < 64; off <<= 1) {
        s_all += __shfl_xor(s_all, off);
        s_pos += __shfl_xor(s_pos, off);
    }
    if ((tid & 63) == 0) { red[tid >> 6] = s_all; red[4 + (tid >> 6)] = s_pos; }
    __syncthreads();
    if (tid == 0)
        unsafeAtomicAdd(&ws->sum_all[blockIdx.x & 7], red[0] + red[1] + red[2] + red[3]);
    if (tid == 1)
        unsafeAtomicAdd(&ws->sum_pos[blockIdx.x & 7], red[4] + red[5] + red[6] + red[7]);
}

// ---------------------------------------------------------------- finalize
__global__ void final_kernel(const Accum* __restrict__ ws, float* __restrict__ out) {
    if (threadIdx.x == 0 && blockIdx.x == 0) {
        long long pos = 0;
        for (int c = 0; c < NCLS; ++c)
            pos += (long long)ws->sup_cnt[c] * (long long)ws->tgt_cnt[c];
        const long long tot = (long long)TARGET * SUPPORT;
        double S = 0.0, P = 0.0;
        for (int i = 0; i < 8; ++i) { S += ws->sum_all[i]; P += ws->sum_pos[i]; }
        out[0] = (float)((S - P) / ((double)pos * (double)(tot - pos)));
        float nll = 0.0f;
        for (int i = 0; i < 8; ++i) nll += ws->nll_sum[i];
        out[1] = nll / (float)TARGET;
    }
}

// ---------------------------------------------------------------- launch
extern "C" void kernel_launch(void* const* d_in, const int* in_sizes, int n_in,
                              void* d_out, int out_size, void* d_ws, size_t ws_size,
                              hipStream_t stream) {
    const float* logits = (const float*)d_in[0];   // (65024, 64) f32
    const float* ip     = (const float*)d_in[1];   // (65024, 512) f32
    const int*   labels = (const int*)d_in[2];     // (65536,) int
    float* out = (float*)d_out;
    Accum* ws  = (Accum*)d_ws;

    prep_kernel<<<1, 512, 0, stream>>>(labels, ws);
    phdir_kernel<<<PH_BLK + DR_BLK, 256, 0, stream>>>(ip, logits, labels, ws);
    cdf_kernel<<<1, 128, 0, stream>>>(ws);
    gather_kernel<<<GS_BLK, 256, 0, stream>>>(ip, labels, ws->cls_off, ws->cls_col, ws);
    final_kernel<<<1, 64, 0, stream>>>(ws, out);
}

// Round 9
// 90.818 us; speedup vs baseline: 3.5751x; 3.5751x over previous
//
#include <hip/hip_runtime.h>

#define SUPPORT 512
#define TARGET  65024
#define NCLS    64
#define NQUAD   (TARGET / 4)       // 16256 row-quads for direct part
#define GS_ROWS 64
#define GS_BLK  (TARGET / GS_ROWS) // 1016 stream blocks
#define PH_BLK  2032               // pos_hist blocks (8 threads/row)
#define DR_BLK  1024               // direct blocks

struct Accum {
    // ---- zeroed by prep ----
    float hist_fr_sp[8][80];    // spread Σfrac per bin (pos elements)
    float hist_cnt_sp[8][80];   // spread counts per bin (pos elements)
    float sum_all[8];
    float sum_pos[8];
    float nll_sum[8];
    int   tgt_cnt[NCLS];
    // ---- fully overwritten, no zeroing needed ----
    float A[80];                // C[idx+1]
    float B[80];                // Hpos[idx+1]
    int   sup_cnt[NCLS];
    int   cls_off[NCLS + 1];
    int   cls_col[SUPPORT];
};
#define ZERO_WORDS (8 * 80 * 2 + 3 * 8 + NCLS)   // 1368 words

__device__ __forceinline__ void lds_fadd(float* p, float v) {
    __hip_atomic_fetch_add(p, v, __ATOMIC_RELAXED, __HIP_MEMORY_SCOPE_WORKGROUP);
}

// ---------------------------------------------------------------- prep (zeroes ws too)
__global__ void prep_kernel(const int* __restrict__ labels, Accum* ws) {
    __shared__ int sh_cnt[NCLS], sh_off[NCLS], cur[NCLS];
    const int t = threadIdx.x;                 // 512 threads
    int* wsi = (int*)ws;
    for (int i = t; i < ZERO_WORDS; i += 512) wsi[i] = 0;
    if (t < NCLS) { sh_cnt[t] = 0; cur[t] = 0; }
    __syncthreads();
    const int c = labels[t];
    atomicAdd(&sh_cnt[c], 1);
    __syncthreads();
    if (t == 0) {
        int o = 0;
        for (int i = 0; i < NCLS; ++i) { sh_off[i] = o; ws->cls_off[i] = o; o += sh_cnt[i]; }
        ws->cls_off[NCLS] = o;
    }
    __syncthreads();
    if (t < NCLS) ws->sup_cnt[t] = sh_cnt[t];
    const int slot = atomicAdd(&cur[c], 1);
    ws->cls_col[sh_off[c] + slot] = t;
}

// ---------------------------------------------------------------- pos_hist + direct (fused dispatch)
__global__ __launch_bounds__(256) void phdir_kernel(const float* __restrict__ ip,
                                                    const float* __restrict__ logits,
                                                    const int* __restrict__ labels,
                                                    Accum* __restrict__ ws) {
    const int tid = threadIdx.x;
    if (blockIdx.x < PH_BLK) {
        // ---- pos (Sfr, Cnt) histogram: 8 threads per target row
        __shared__ float hfr[76][8];
        __shared__ float hcnt[76][8];
        __shared__ int   colL[SUPPORT];
        __shared__ int   offL[NCLS + 1];
        for (int i = tid; i < 76 * 8; i += 256) {
            (&hfr[0][0])[i] = 0.0f;
            (&hcnt[0][0])[i] = 0.0f;
        }
        for (int i = tid; i < SUPPORT; i += 256) colL[i] = ws->cls_col[i];
        if (tid <= NCLS) offL[tid] = ws->cls_off[tid];
        __syncthreads();

        const int row = (blockIdx.x * 256 + tid) >> 3;
        const int sl  = tid & 7;
        {
            const int c    = labels[SUPPORT + row];
            const int base = offL[c];
            const int cnt  = offL[c + 1] - base;
            const float* rptr = ip + (size_t)row * SUPPORT;
            for (int j = sl; j < cnt; j += 8) {
                const float s  = rptr[colL[base + j]];
                const float u  = s * 75.0f;
                const float fl = floorf(u);
                const float fr = u - fl;
                const int idx  = (int)fl;            // 0..74 guaranteed (s in [0,1))
                lds_fadd(&hfr[idx][sl],  fr);
                lds_fadd(&hcnt[idx][sl], 1.0f);
            }
        }
        __syncthreads();
        if (tid < 76) {
            float a = 0.0f, b = 0.0f;
            #pragma unroll
            for (int r = 0; r < 8; ++r) { a += hfr[tid][r]; b += hcnt[tid][r]; }
            if (a != 0.0f) unsafeAtomicAdd(&ws->hist_fr_sp[blockIdx.x & 7][tid], a);
            if (b != 0.0f) unsafeAtomicAdd(&ws->hist_cnt_sp[blockIdx.x & 7][tid], b);
        }
    } else {
        // ---- direct loss: 4 rows per wave, 16-lane group per row
        __shared__ int   ltc[NCLS];
        __shared__ float wsum[4];
        if (tid < NCLS) ltc[tid] = 0;
        __syncthreads();

        const int bid  = blockIdx.x - PH_BLK;
        const int wid  = tid >> 6;
        const int lane = tid & 63;
        const int sub  = lane >> 4;
        const int grpb = lane & ~15;

        float lsum = 0.0f;
        for (int q = bid * 4 + wid; q < NQUAD; q += DR_BLK * 4) {
            const float4 x = reinterpret_cast<const float4*>(logits)[q * 64 + lane];
            const int lab  = labels[SUPPORT + q * 4 + sub];
            float m = fmaxf(fmaxf(x.x, x.y), fmaxf(x.z, x.w));
            #pragma unroll
            for (int off = 1; off < 16; off <<= 1) m = fmaxf(m, __shfl_xor(m, off));
            float e = __expf(x.x - m) + __expf(x.y - m) + __expf(x.z - m) + __expf(x.w - m);
            #pragma unroll
            for (int off = 1; off < 16; off <<= 1) e += __shfl_xor(e, off);
            const int l3 = lab & 3;
            const float sel = l3 == 0 ? x.x : l3 == 1 ? x.y : l3 == 2 ? x.z : x.w;
            const float xl = __shfl(sel, grpb + (lab >> 2));
            if ((lane & 15) == 0) {
                lsum += m + __logf(e) - xl;
                atomicAdd(&ltc[lab], 1);
            }
        }
        #pragma unroll
        for (int off = 1; off < 64; off <<= 1) lsum += __shfl_xor(lsum, off);
        if (lane == 0) wsum[wid] = lsum;
        __syncthreads();
        if (tid == 0)
            unsafeAtomicAdd(&ws->nll_sum[bid & 7], wsum[0] + wsum[1] + wsum[2] + wsum[3]);
        if (tid < NCLS) {
            int v = ltc[tid];
            if (v) atomicAdd(&ws->tgt_cnt[tid], v);
        }
    }
}

// ---------------------------------------------------------------- cdf build + closed-form sum_pos
__global__ void cdf_kernel(Accum* ws) {
    __shared__ float Sfr[80], Cnt[80];
    const int t = threadIdx.x;
    if (t < 76) {
        float a = 0.0f, b = 0.0f;
        #pragma unroll
        for (int r = 0; r < 8; ++r) { a += ws->hist_fr_sp[r][t]; b += ws->hist_cnt_sp[r][t]; }
        Sfr[t] = a; Cnt[t] = b;
    }
    if (t >= 76 && t < 80) { Sfr[t] = 0.0f; Cnt[t] = 0.0f; }
    __syncthreads();
    if (t == 0) {
        float H[77], C[77];
        H[0] = Sfr[0];
        for (int i = 1; i < 77; ++i) H[i] = Sfr[i] + Cnt[i - 1] - Sfr[i - 1];
        float cacc = 0.0f;
        for (int i = 0; i < 77; ++i) { cacc += H[i]; C[i] = cacc; }
        for (int idx = 0; idx < 76; ++idx) { ws->A[idx] = C[idx + 1]; ws->B[idx] = H[idx + 1]; }
        for (int i = 76; i < 80; ++i) { ws->A[i] = 0.0f; ws->B[i] = 0.0f; }
        // sum_pos = sum_k Cnt[k]*C[k+1] - Sfr[k]*H[k+1]
        double sp = 0.0;
        for (int k = 0; k < 75; ++k)
            sp += (double)Cnt[k] * (double)C[k + 1] - (double)Sfr[k] * (double)H[k + 1];
        ws->sum_pos[0] = (float)sp;
    }
}

// ---------------------------------------------------------------- main pass
// Pure stream: block owns 64 contiguous rows (32 steps x 256 float4).
// Named-register 8-deep load pipeline; per element ~9 VALU + 1 staggered
// ds_read_b64. No masks, no labels, no second pass.
__global__ __launch_bounds__(256, 4) void gather_kernel(const float* __restrict__ ip,
                                                        Accum* __restrict__ ws) {
    __shared__ float2 tab[76 * 16];   // 16-way replicated, idx-staggered
    __shared__ float red[4];
    const int tid = threadIdx.x;
    const int c16 = tid & 15;

    for (int i = tid; i < 76 * 16; i += 256) {
        const int idx = i >> 4, cc = i & 15;
        tab[(idx << 4) + ((cc + idx) & 15)] = make_float2(ws->A[idx], ws->B[idx]);
    }
    __syncthreads();

    const float4* base = reinterpret_cast<const float4*>(ip)
                       + (size_t)blockIdx.x * (GS_ROWS * 128) + tid;

    float s0 = 0.0f, s1 = 0.0f;
    float4 qa0, qa1, qa2, qa3, qa4, qa5, qa6, qa7;
    float4 qb0, qb1, qb2, qb3, qb4, qb5, qb6, qb7;

#define LDA(T) { qa0 = base[((T)+0)*256]; qa1 = base[((T)+1)*256]; \
                 qa2 = base[((T)+2)*256]; qa3 = base[((T)+3)*256]; \
                 qa4 = base[((T)+4)*256]; qa5 = base[((T)+5)*256]; \
                 qa6 = base[((T)+6)*256]; qa7 = base[((T)+7)*256]; }
#define LDB(T) { qb0 = base[((T)+0)*256]; qb1 = base[((T)+1)*256]; \
                 qb2 = base[((T)+2)*256]; qb3 = base[((T)+3)*256]; \
                 qb4 = base[((T)+4)*256]; qb5 = base[((T)+5)*256]; \
                 qb6 = base[((T)+6)*256]; qb7 = base[((T)+7)*256]; }
#define PE(S, ACC) { const float u = (S) * 75.0f; const float fl = floorf(u);     \
                     const float fr = u - fl; const int idx = (int)fl;            \
                     const float2 ab = tab[(idx << 4) + ((c16 + idx) & 15)];      \
                     ACC += fmaf(-fr, ab.y, ab.x); }
#define P1(Q) { PE(Q.x, s0) PE(Q.y, s1) PE(Q.z, s0) PE(Q.w, s1) }
#define PA()  { P1(qa0) P1(qa1) P1(qa2) P1(qa3) P1(qa4) P1(qa5) P1(qa6) P1(qa7) }
#define PB()  { P1(qb0) P1(qb1) P1(qb2) P1(qb3) P1(qb4) P1(qb5) P1(qb6) P1(qb7) }

    LDA(0);
    LDB(8);
    PA();  LDA(16);
    PB();  LDB(24);
    PA();
    PB();

#undef LDA
#undef LDB
#undef PE
#undef P1
#undef PA
#undef PB

    float s_all = s0 + s1;
    #pragma unroll
    for (int off = 1; off < 64; off <<= 1) s_all += __shfl_xor(s_all, off);
    if ((tid & 63) == 0) red[tid >> 6] = s_all;
    __syncthreads();
    if (tid == 0)
        unsafeAtomicAdd(&ws->sum_all[blockIdx.x & 7], red[0] + red[1] + red[2] + red[3]);
}

// ---------------------------------------------------------------- finalize
__global__ void final_kernel(const Accum* __restrict__ ws, float* __restrict__ out) {
    if (threadIdx.x == 0 && blockIdx.x == 0) {
        long long pos = 0;
        for (int c = 0; c < NCLS; ++c)
            pos += (long long)ws->sup_cnt[c] * (long long)ws->tgt_cnt[c];
        const long long tot = (long long)TARGET * SUPPORT;
        double S = 0.0, P = 0.0;
        for (int i = 0; i < 8; ++i) { S += ws->sum_all[i]; P += ws->sum_pos[i]; }
        out[0] = (float)((S - P) / ((double)pos * (double)(tot - pos)));
        float nll = 0.0f;
        for (int i = 0; i < 8; ++i) nll += ws->nll_sum[i];
        out[1] = nll / (float)TARGET;
    }
}

// ---------------------------------------------------------------- launch
extern "C" void kernel_launch(void* const* d_in, const int* in_sizes, int n_in,
                              void* d_out, int out_size, void* d_ws, size_t ws_size,
                              hipStream_t stream) {
    const float* logits = (const float*)d_in[0];   // (65024, 64) f32
    const float* ip     = (const float*)d_in[1];   // (65024, 512) f32
    const int*   labels = (const int*)d_in[2];     // (65536,) int
    float* out = (float*)d_out;
    Accum* ws  = (Accum*)d_ws;

    prep_kernel<<<1, 512, 0, stream>>>(labels, ws);
    phdir_kernel<<<PH_BLK + DR_BLK, 256, 0, stream>>>(ip, logits, labels, ws);
    cdf_kernel<<<1, 128, 0, stream>>>(ws);
    gather_kernel<<<GS_BLK, 256, 0, stream>>>(ip, ws);
    final_kernel<<<1, 64, 0, stream>>>(ws, out);
}